// Round 6
// baseline (249.909 us; speedup 1.0000x reference)
//
#include <hip/hip_runtime.h>
#include <stdint.h>

typedef __attribute__((ext_vector_type(4))) int i32x4;

#define M_DIM 8192
#define N_DIM 8192
#define K_DIM 2048
#define BK 128           // i8 elements per K-tile (128 B per row)
#define NT (K_DIM / BK)  // 16 K-tiles

// ---- pre-pass: per-row i8 quantization of x, exact ternarize of W to i8 ----
__global__ __launch_bounds__(256)
void tl_quant(const float* __restrict__ x, const float* __restrict__ W,
              signed char* __restrict__ xq, signed char* __restrict__ wq,
              float* __restrict__ srow) {
  __shared__ float smax[4];
  const int row = blockIdx.x;
  const int t = threadIdx.x;

  const float* xr = x + (size_t)row * K_DIM;
  float4 v0 = reinterpret_cast<const float4*>(xr)[t * 2];
  float4 v1 = reinterpret_cast<const float4*>(xr)[t * 2 + 1];
  float m = fmaxf(fmaxf(fmaxf(fabsf(v0.x), fabsf(v0.y)), fmaxf(fabsf(v0.z), fabsf(v0.w))),
                  fmaxf(fmaxf(fabsf(v1.x), fabsf(v1.y)), fmaxf(fabsf(v1.z), fabsf(v1.w))));
  #pragma unroll
  for (int off = 1; off < 64; off <<= 1)
    m = fmaxf(m, __shfl_xor(m, off, 64));
  if ((t & 63) == 0) smax[t >> 6] = m;
  __syncthreads();
  m = fmaxf(fmaxf(smax[0], smax[1]), fmaxf(smax[2], smax[3]));
  const float rs = (m > 0.f) ? 127.0f / m : 0.f;

  union { signed char c[8]; uint2 u; } qx;
  qx.c[0] = (signed char)__float2int_rn(v0.x * rs);
  qx.c[1] = (signed char)__float2int_rn(v0.y * rs);
  qx.c[2] = (signed char)__float2int_rn(v0.z * rs);
  qx.c[3] = (signed char)__float2int_rn(v0.w * rs);
  qx.c[4] = (signed char)__float2int_rn(v1.x * rs);
  qx.c[5] = (signed char)__float2int_rn(v1.y * rs);
  qx.c[6] = (signed char)__float2int_rn(v1.z * rs);
  qx.c[7] = (signed char)__float2int_rn(v1.w * rs);
  reinterpret_cast<uint2*>(xq + (size_t)row * K_DIM)[t] = qx.u;

  const float* wr = W + (size_t)row * K_DIM;
  float4 w0 = reinterpret_cast<const float4*>(wr)[t * 2];
  float4 w1 = reinterpret_cast<const float4*>(wr)[t * 2 + 1];
  union { signed char c[8]; uint2 u; } qw;
  qw.c[0] = (fabsf(w0.x) > 0.4f) ? ((w0.x > 0.f) ? 1 : -1) : 0;
  qw.c[1] = (fabsf(w0.y) > 0.4f) ? ((w0.y > 0.f) ? 1 : -1) : 0;
  qw.c[2] = (fabsf(w0.z) > 0.4f) ? ((w0.z > 0.f) ? 1 : -1) : 0;
  qw.c[3] = (fabsf(w0.w) > 0.4f) ? ((w0.w > 0.f) ? 1 : -1) : 0;
  qw.c[4] = (fabsf(w1.x) > 0.4f) ? ((w1.x > 0.f) ? 1 : -1) : 0;
  qw.c[5] = (fabsf(w1.y) > 0.4f) ? ((w1.y > 0.f) ? 1 : -1) : 0;
  qw.c[6] = (fabsf(w1.z) > 0.4f) ? ((w1.z > 0.f) ? 1 : -1) : 0;
  qw.c[7] = (fabsf(w1.w) > 0.4f) ? ((w1.w > 0.f) ? 1 : -1) : 0;
  reinterpret_cast<uint2*>(wq + (size_t)row * K_DIM)[t] = qw.u;

  if (t == 0) srow[row] = (m > 0.f) ? m / 127.0f : 0.f;
}

// ---- i8 GEMM: C[t,o] = srow[t] * sum_k xq[t,k]*wq[o,k] ----
// R5 structure (128x128 tile, 4 waves 2x2, byte XOR swizzle both-sides,
// 0 conflicts) + 1-tile-deep double-buffer with counted vmcnt(8):
// invariant at loop top: tile T resident in buf[T&1], tile T+1's 8 per-wave
// loads in flight. Body: compute(T) -> barrier (all reads of buf[T&1] done)
// -> stage T+2 into buf[T&1] -> vmcnt(8) (drain T+1 only) -> barrier.
// Tail stages wrap to kt=0/128 (L2-hot dummies) to keep the count constant.
__global__ __launch_bounds__(256, 2)
void tl_gemm(const signed char* __restrict__ A, const signed char* __restrict__ B,
             const float* __restrict__ srow, float* __restrict__ C) {
  __shared__ signed char sA[2][128 * 128];   // 2 x 16 KiB
  __shared__ signed char sB[2][128 * 128];   // 2 x 16 KiB

  const int tid  = threadIdx.x;
  const int lane = tid & 63;
  const int w    = tid >> 6;       // wave 0..3
  const int wr   = w >> 1;
  const int wc   = w & 1;

  // XCD-aware bijective swizzle: nwg = 4096 = 8 * 512
  int bid = blockIdx.x;
  int swz = (bid & 7) * (4096 / 8) + (bid >> 3);
  const int tm = swz >> 6;
  const int tn = swz & 63;
  const size_t brow = (size_t)tm * 128;
  const size_t bcol = (size_t)tn * 128;

  // staging: per issue a wave covers 8 rows x 128 B (64 lanes x 16 B)
  const int srow0 = w * 32 + (lane >> 3);                    // + j*8
  const int scolb = ((lane & 7) * 16) ^ ((srow0 & 7) << 4);  // swizzled source col (j-invariant)
  const signed char* gA0 = A + (brow + srow0) * (size_t)K_DIM + scolb;
  const signed char* gB0 = B + (bcol + srow0) * (size_t)K_DIM + scolb;

#define STAGE(bufi, kt) do {                                                          \
    _Pragma("unroll")                                                                 \
    for (int j = 0; j < 4; ++j) {                                                     \
      const signed char* ga = gA0 + (size_t)j * 8 * K_DIM + (kt);                     \
      const signed char* gb = gB0 + (size_t)j * 8 * K_DIM + (kt);                     \
      signed char* la = &sA[bufi][(w * 32 + j * 8) * 128];                            \
      signed char* lb = &sB[bufi][(w * 32 + j * 8) * 128];                            \
      __builtin_amdgcn_global_load_lds((const __attribute__((address_space(1))) void*)ga, \
          (__attribute__((address_space(3))) void*)la, 16, 0, 0);                     \
      __builtin_amdgcn_global_load_lds((const __attribute__((address_space(1))) void*)gb, \
          (__attribute__((address_space(3))) void*)lb, 16, 0, 0);                     \
    }                                                                                 \
  } while (0)

  i32x4 acc[4][4];
  #pragma unroll
  for (int i = 0; i < 4; ++i)
    #pragma unroll
    for (int j = 0; j < 4; ++j)
      acc[i][j] = i32x4{0, 0, 0, 0};

  const int fr = lane & 15;        // fragment row
  const int k8 = lane >> 4;        // k-group 0..3

  // ---- prologue: tile 0 -> buf0, tile 1 -> buf1 ----
  STAGE(0, 0);
  STAGE(1, BK);
  asm volatile("s_waitcnt vmcnt(8)" ::: "memory");   // tile 0 resident; tile 1 in flight
  __builtin_amdgcn_s_barrier();
  __builtin_amdgcn_sched_barrier(0);

  for (int T = 0; T < NT; ++T) {
    const int c = T & 1;

    // ---- compute tile T from buf[c] ----
    #pragma unroll
    for (int kk = 0; kk < 2; ++kk) {
      i32x4 av[4], bv[4];
      #pragma unroll
      for (int mi = 0; mi < 4; ++mi) {
        int row  = wr * 64 + mi * 16 + fr;
        int colb = (kk * 64 + k8 * 16) ^ ((row & 7) << 4);
        av[mi] = *(const i32x4*)&sA[c][row * 128 + colb];
      }
      #pragma unroll
      for (int ni = 0; ni < 4; ++ni) {
        int row  = wc * 64 + ni * 16 + fr;
        int colb = (kk * 64 + k8 * 16) ^ ((row & 7) << 4);
        bv[ni] = *(const i32x4*)&sB[c][row * 128 + colb];
      }
      #pragma unroll
      for (int mi = 0; mi < 4; ++mi)
        #pragma unroll
        for (int ni = 0; ni < 4; ++ni)
          acc[mi][ni] = __builtin_amdgcn_mfma_i32_16x16x64_i8(av[mi], bv[ni], acc[mi][ni], 0, 0, 0);
    }

    // all reads of buf[c] consumed (MFMAs above forced lgkm waits)
    __builtin_amdgcn_s_barrier();
    __builtin_amdgcn_sched_barrier(0);

    // stage tile T+2 into buf[c] (tail iterations: wrapped L2-hot dummy)
    STAGE(c, ((T + 2) & (NT - 1)) * BK);
    // drain tile T+1's 8 loads; keep tile T+2's 8 in flight
    asm volatile("s_waitcnt vmcnt(8)" ::: "memory");
    __builtin_amdgcn_s_barrier();
    __builtin_amdgcn_sched_barrier(0);
  }

  // drain dummy stages before epilogue
  asm volatile("s_waitcnt vmcnt(0)" ::: "memory");

  // ---- epilogue: C/D layout col = lane&15, row = (lane>>4)*4 + reg; scale by srow ----
  #pragma unroll
  for (int mi = 0; mi < 4; ++mi) {
    size_t r0 = brow + wr * 64 + mi * 16 + k8 * 4;
    float sc0 = srow[r0 + 0], sc1 = srow[r0 + 1], sc2 = srow[r0 + 2], sc3 = srow[r0 + 3];
    #pragma unroll
    for (int ni = 0; ni < 4; ++ni) {
      i32x4 v = acc[mi][ni];
      size_t c0 = bcol + wc * 64 + ni * 16 + fr;
      C[(r0 + 0) * N_DIM + c0] = sc0 * (float)v[0];
      C[(r0 + 1) * N_DIM + c0] = sc1 * (float)v[1];
      C[(r0 + 2) * N_DIM + c0] = sc2 * (float)v[2];
      C[(r0 + 3) * N_DIM + c0] = sc3 * (float)v[3];
    }
  }
#undef STAGE
}

// Fallback (only if ws_size is unexpectedly small): fused ternarize + fp32 tiled GEMM.
__global__ void tl_naive(const float* __restrict__ x, const float* __restrict__ W,
                         float* __restrict__ out) {
  __shared__ float sx[16][17];
  __shared__ float sw[16][17];
  int tx = threadIdx.x, ty = threadIdx.y;
  int row = blockIdx.y * 16 + ty;
  int col = blockIdx.x * 16 + tx;
  float acc = 0.f;
  for (int kt = 0; kt < K_DIM; kt += 16) {
    sx[ty][tx] = x[(size_t)row * K_DIM + kt + tx];
    float wv = W[(size_t)(blockIdx.x * 16 + ty) * K_DIM + kt + tx];
    sw[ty][tx] = (fabsf(wv) > 0.4f) ? ((wv > 0.f) ? 1.f : -1.f) : 0.f;
    __syncthreads();
    #pragma unroll
    for (int k = 0; k < 16; ++k) acc += sx[ty][k] * sw[tx][k];
    __syncthreads();
  }
  out[(size_t)row * N_DIM + col] = acc;
}

extern "C" void kernel_launch(void* const* d_in, const int* in_sizes, int n_in,
                              void* d_out, int out_size, void* d_ws, size_t ws_size,
                              hipStream_t stream) {
  const float* x = (const float*)d_in[0];
  const float* W = (const float*)d_in[1];
  float* out = (float*)d_out;

  const size_t xq_bytes = (size_t)M_DIM * K_DIM;          // 16 MiB
  const size_t wq_bytes = (size_t)N_DIM * K_DIM;          // 16 MiB
  const size_t need = xq_bytes + wq_bytes + M_DIM * sizeof(float);

  if (ws_size >= need) {
    signed char* xq = (signed char*)d_ws;
    signed char* wq = xq + xq_bytes;
    float* srow = (float*)(wq + wq_bytes);
    tl_quant<<<M_DIM, 256, 0, stream>>>(x, W, xq, wq, srow);
    tl_gemm<<<4096, 256, 0, stream>>>(xq, wq, srow, out);
  } else {
    dim3 g(N_DIM / 16, M_DIM / 16), b(16, 16);
    tl_naive<<<g, b, 0, stream>>>(x, W, out);
  }
}

// Round 7
// 185.636 us; speedup vs baseline: 1.3462x; 1.3462x over previous
//
#include <hip/hip_runtime.h>
#include <stdint.h>

typedef __attribute__((ext_vector_type(4))) int i32x4;

#define M_DIM 8192
#define N_DIM 8192
#define K_DIM 2048
#define BK 128           // i8 elements per K-tile (128 B per row)
#define NT (K_DIM / BK)  // 16 K-tiles

// ---- pre-pass: per-row i8 quantization of x, exact ternarize of W to i8 ----
__global__ __launch_bounds__(256)
void tl_quant(const float* __restrict__ x, const float* __restrict__ W,
              signed char* __restrict__ xq, signed char* __restrict__ wq,
              float* __restrict__ srow) {
  __shared__ float smax[4];
  const int row = blockIdx.x;
  const int t = threadIdx.x;

  const float* xr = x + (size_t)row * K_DIM;
  float4 v0 = reinterpret_cast<const float4*>(xr)[t * 2];
  float4 v1 = reinterpret_cast<const float4*>(xr)[t * 2 + 1];
  float m = fmaxf(fmaxf(fmaxf(fabsf(v0.x), fabsf(v0.y)), fmaxf(fabsf(v0.z), fabsf(v0.w))),
                  fmaxf(fmaxf(fabsf(v1.x), fabsf(v1.y)), fmaxf(fabsf(v1.z), fabsf(v1.w))));
  #pragma unroll
  for (int off = 1; off < 64; off <<= 1)
    m = fmaxf(m, __shfl_xor(m, off, 64));
  if ((t & 63) == 0) smax[t >> 6] = m;
  __syncthreads();
  m = fmaxf(fmaxf(smax[0], smax[1]), fmaxf(smax[2], smax[3]));
  const float rs = (m > 0.f) ? 127.0f / m : 0.f;

  union { signed char c[8]; uint2 u; } qx;
  qx.c[0] = (signed char)__float2int_rn(v0.x * rs);
  qx.c[1] = (signed char)__float2int_rn(v0.y * rs);
  qx.c[2] = (signed char)__float2int_rn(v0.z * rs);
  qx.c[3] = (signed char)__float2int_rn(v0.w * rs);
  qx.c[4] = (signed char)__float2int_rn(v1.x * rs);
  qx.c[5] = (signed char)__float2int_rn(v1.y * rs);
  qx.c[6] = (signed char)__float2int_rn(v1.z * rs);
  qx.c[7] = (signed char)__float2int_rn(v1.w * rs);
  reinterpret_cast<uint2*>(xq + (size_t)row * K_DIM)[t] = qx.u;

  const float* wr = W + (size_t)row * K_DIM;
  float4 w0 = reinterpret_cast<const float4*>(wr)[t * 2];
  float4 w1 = reinterpret_cast<const float4*>(wr)[t * 2 + 1];
  union { signed char c[8]; uint2 u; } qw;
  qw.c[0] = (fabsf(w0.x) > 0.4f) ? ((w0.x > 0.f) ? 1 : -1) : 0;
  qw.c[1] = (fabsf(w0.y) > 0.4f) ? ((w0.y > 0.f) ? 1 : -1) : 0;
  qw.c[2] = (fabsf(w0.z) > 0.4f) ? ((w0.z > 0.f) ? 1 : -1) : 0;
  qw.c[3] = (fabsf(w0.w) > 0.4f) ? ((w0.w > 0.f) ? 1 : -1) : 0;
  qw.c[4] = (fabsf(w1.x) > 0.4f) ? ((w1.x > 0.f) ? 1 : -1) : 0;
  qw.c[5] = (fabsf(w1.y) > 0.4f) ? ((w1.y > 0.f) ? 1 : -1) : 0;
  qw.c[6] = (fabsf(w1.z) > 0.4f) ? ((w1.z > 0.f) ? 1 : -1) : 0;
  qw.c[7] = (fabsf(w1.w) > 0.4f) ? ((w1.w > 0.f) ? 1 : -1) : 0;
  reinterpret_cast<uint2*>(wq + (size_t)row * K_DIM)[t] = qw.u;

  if (t == 0) srow[row] = (m > 0.f) ? m / 127.0f : 0.f;
}

// ---- i8 GEMM: C[t,o] = srow[t] * sum_k xq[t,k]*wq[o,k] ----
// R5 structure verbatim (128x128 tile, 4 waves 2x2, single-buffer 2-barrier
// loop, byte XOR swizzle (row&7)<<4 both-sides, 0 conflicts). Changes vs R5:
// (1) __launch_bounds__(256,4): VGPR+AGPR=124 fits the 128 cap -> 4 blocks/CU
//     (R5 was capped at 3 by the bound, not by LDS=32KiB).
// (2) supertile raster: each XCD owns a 8(tm) x 64(tn) region, walked in
//     8x8 supertiles -> concurrent L2 working set ~5 MB instead of ~24 MB.
__global__ __launch_bounds__(256, 4)
void tl_gemm(const signed char* __restrict__ A, const signed char* __restrict__ B,
             const float* __restrict__ srow, float* __restrict__ C) {
  __shared__ signed char sA[128 * 128];   // 16 KiB
  __shared__ signed char sB[128 * 128];   // 16 KiB

  const int tid  = threadIdx.x;
  const int lane = tid & 63;
  const int w    = tid >> 6;       // wave 0..3
  const int wr   = w >> 1;         // wave row (0..1)
  const int wc   = w & 1;          // wave col (0..1)

  // XCD-aware supertile raster: nwg = 4096 = 8 XCDs x 8 supertiles x 64 tiles.
  // xcd gets tm in [xcd*8, xcd*8+8); within, 8x8 supertiles (tm-major inside).
  const int bid = blockIdx.x;
  const int xcd = bid & 7;
  const int idx = bid >> 3;        // 0..511
  const int s   = idx >> 6;        // supertile 0..7 (tn band)
  const int t   = idx & 63;
  const int tm  = xcd * 8 + (t & 7);
  const int tn  = s * 8 + (t >> 3);
  const size_t brow = (size_t)tm * 128;
  const size_t bcol = (size_t)tn * 128;

  // staging: per issue a wave covers 8 rows x 128 B (64 lanes x 16 B)
  const int srow0  = w * 32 + (lane >> 3);
  const int scolb0 = (lane & 7) * 16;          // byte col base

  i32x4 acc[4][4];
  #pragma unroll
  for (int i = 0; i < 4; ++i)
    #pragma unroll
    for (int j = 0; j < 4; ++j)
      acc[i][j] = i32x4{0, 0, 0, 0};

  const int fr = lane & 15;        // fragment row
  const int k8 = lane >> 4;        // k-group 0..3

  for (int kt = 0; kt < K_DIM; kt += BK) {
    // ---- stage A,B tiles (linear LDS dest, swizzled global source) ----
    #pragma unroll
    for (int j = 0; j < 4; ++j) {
      int row  = srow0 + j * 8;
      int colb = scolb0 ^ ((row & 7) << 4);
      const signed char* ga = A + (brow + row) * (size_t)K_DIM + kt + colb;
      const signed char* gb = B + (bcol + row) * (size_t)K_DIM + kt + colb;
      signed char* la = &sA[(w * 32 + j * 8) * 128];   // wave-uniform base
      signed char* lb = &sB[(w * 32 + j * 8) * 128];
      __builtin_amdgcn_global_load_lds((const __attribute__((address_space(1))) void*)ga,
                                       (__attribute__((address_space(3))) void*)la, 16, 0, 0);
      __builtin_amdgcn_global_load_lds((const __attribute__((address_space(1))) void*)gb,
                                       (__attribute__((address_space(3))) void*)lb, 16, 0, 0);
    }
    __syncthreads();   // drains vmcnt before any wave reads LDS

    // ---- compute: 2 k-halves (64 elems each) x 16 MFMA ----
    #pragma unroll
    for (int kk = 0; kk < 2; ++kk) {
      i32x4 av[4], bv[4];
      #pragma unroll
      for (int mi = 0; mi < 4; ++mi) {
        int row  = wr * 64 + mi * 16 + fr;
        int colb = (kk * 64 + k8 * 16) ^ ((row & 7) << 4);
        av[mi] = *(const i32x4*)&sA[row * 128 + colb];
      }
      #pragma unroll
      for (int ni = 0; ni < 4; ++ni) {
        int row  = wc * 64 + ni * 16 + fr;
        int colb = (kk * 64 + k8 * 16) ^ ((row & 7) << 4);
        bv[ni] = *(const i32x4*)&sB[row * 128 + colb];
      }
      #pragma unroll
      for (int mi = 0; mi < 4; ++mi)
        #pragma unroll
        for (int ni = 0; ni < 4; ++ni)
          acc[mi][ni] = __builtin_amdgcn_mfma_i32_16x16x64_i8(av[mi], bv[ni], acc[mi][ni], 0, 0, 0);
    }
    __syncthreads();
  }

  // ---- epilogue: C/D layout col = lane&15, row = (lane>>4)*4 + reg; scale by srow ----
  #pragma unroll
  for (int mi = 0; mi < 4; ++mi) {
    size_t r0 = brow + wr * 64 + mi * 16 + k8 * 4;
    float sc0 = srow[r0 + 0], sc1 = srow[r0 + 1], sc2 = srow[r0 + 2], sc3 = srow[r0 + 3];
    #pragma unroll
    for (int ni = 0; ni < 4; ++ni) {
      i32x4 v = acc[mi][ni];
      size_t c0 = bcol + wc * 64 + ni * 16 + fr;
      C[(r0 + 0) * N_DIM + c0] = sc0 * (float)v[0];
      C[(r0 + 1) * N_DIM + c0] = sc1 * (float)v[1];
      C[(r0 + 2) * N_DIM + c0] = sc2 * (float)v[2];
      C[(r0 + 3) * N_DIM + c0] = sc3 * (float)v[3];
    }
  }
}

// Fallback (only if ws_size is unexpectedly small): fused ternarize + fp32 tiled GEMM.
__global__ void tl_naive(const float* __restrict__ x, const float* __restrict__ W,
                         float* __restrict__ out) {
  __shared__ float sx[16][17];
  __shared__ float sw[16][17];
  int tx = threadIdx.x, ty = threadIdx.y;
  int row = blockIdx.y * 16 + ty;
  int col = blockIdx.x * 16 + tx;
  float acc = 0.f;
  for (int kt = 0; kt < K_DIM; kt += 16) {
    sx[ty][tx] = x[(size_t)row * K_DIM + kt + tx];
    float wv = W[(size_t)(blockIdx.x * 16 + ty) * K_DIM + kt + tx];
    sw[ty][tx] = (fabsf(wv) > 0.4f) ? ((wv > 0.f) ? 1.f : -1.f) : 0.f;
    __syncthreads();
    #pragma unroll
    for (int k = 0; k < 16; ++k) acc += sx[ty][k] * sw[tx][k];
    __syncthreads();
  }
  out[(size_t)row * N_DIM + col] = acc;
}

extern "C" void kernel_launch(void* const* d_in, const int* in_sizes, int n_in,
                              void* d_out, int out_size, void* d_ws, size_t ws_size,
                              hipStream_t stream) {
  const float* x = (const float*)d_in[0];
  const float* W = (const float*)d_in[1];
  float* out = (float*)d_out;

  const size_t xq_bytes = (size_t)M_DIM * K_DIM;          // 16 MiB
  const size_t wq_bytes = (size_t)N_DIM * K_DIM;          // 16 MiB
  const size_t need = xq_bytes + wq_bytes + M_DIM * sizeof(float);

  if (ws_size >= need) {
    signed char* xq = (signed char*)d_ws;
    signed char* wq = xq + xq_bytes;
    float* srow = (float*)(wq + wq_bytes);
    tl_quant<<<M_DIM, 256, 0, stream>>>(x, W, xq, wq, srow);
    tl_gemm<<<4096, 256, 0, stream>>>(xq, wq, srow, out);
  } else {
    dim3 g(N_DIM / 16, M_DIM / 16), b(16, 16);
    tl_naive<<<g, b, 0, stream>>>(x, W, out);
  }
}